// Round 17
// baseline (188.451 us; speedup 1.0000x reference)
//
#include <hip/hip_runtime.h>
#include <cstddef>

#define CAPD 64
#define BSZ 512        // nodes per bucket (p3 granularity)
#define BSH 9          // log2(BSZ)
#define CHUNK 8192     // edges per partition block
#define BCAP 12288     // per-bucket edge capacity (mean 8163, sigma ~90 -> safe)

typedef unsigned int uint;
typedef unsigned short ushort;
typedef unsigned char uchar;
typedef float f32x4 __attribute__((ext_vector_type(4)));
typedef _Float16 f16x8 __attribute__((ext_vector_type(8)));  // 8 fp16 = 4 VGPRs

// fp16 helpers: word = dimEven | dimOdd<<16
__device__ inline float h_lo(uint v) {
    union { ushort u; _Float16 h; } c; c.u = (ushort)(v & 0xFFFFu); return (float)c.h;
}
__device__ inline float h_hi(uint v) {
    union { ushort u; _Float16 h; } c; c.u = (ushort)(v >> 16); return (float)c.h;
}
__device__ inline ushort h_bits(float x) {
    union { _Float16 h; ushort u; } c; c.h = (_Float16)x; return c.u;
}
__device__ inline uint h_pack(float a, float b) {
    return (uint)h_bits(a) | ((uint)h_bits(b) << 16);
}
// biased-uint8 byte k -> float (maps to v_cvt_f32_ubyte[k])
__device__ inline float ub0(uint v) { return (float)(v & 0xFFu); }
__device__ inline float ub1(uint v) { return (float)((v >> 8) & 0xFFu); }
__device__ inline float ub2(uint v) { return (float)((v >> 16) & 0xFFu); }
__device__ inline float ub3(uint v) { return (float)(v >> 24); }

// ---------- p3: partition (blocks [0,NB2)) + W transposes (2 tail blocks) ----------
__global__ __launch_bounds__(256) void p3_scatter(const int* __restrict__ esrc,
                                                  const int* __restrict__ edst, int E,
                                                  int nb, int NB2,
                                                  int* __restrict__ bucketCursor,
                                                  unsigned* __restrict__ gSorted,
                                                  const float* __restrict__ W1,
                                                  const float* __restrict__ W2,
                                                  uint* __restrict__ Wt1,
                                                  uint* __restrict__ Wt2) {
    __shared__ __align__(16) char SHB[78848];  // 77KB
    int bid = blockIdx.x, tid = threadIdx.x;
    if (bid >= NB2) {
        const float* W = (bid - NB2) ? W2 : W1;
        uint* O = (bid - NB2) ? Wt2 : Wt1;
        float (*ws)[129] = (float(*)[129])SHB;
#pragma unroll
        for (int j = 0; j < 16; ++j) {
            int q = tid + 256 * j;
            int k = q >> 5, c = (q & 31) * 4;
            float4 v = *reinterpret_cast<const float4*>(W + k * 128 + c);
            ws[k][c] = v.x; ws[k][c + 1] = v.y; ws[k][c + 2] = v.z; ws[k][c + 3] = v.w;
        }
        __syncthreads();
#pragma unroll
        for (int j = 0; j < 32; ++j) {
            int q = tid + 256 * j;
            int ncol = q >> 6, kw = q & 63;
            O[q] = h_pack(ws[2 * kw][ncol], ws[2 * kw + 1][ncol]);
        }
        return;
    }
    uint*  payL = (uint*)SHB;                 // 32KB
    uint*  outL = (uint*)(SHB + 32768);       // 32KB
    uchar* bktL = (uchar*)(SHB + 65536);      // 8KB
    int*   hist   = (int*)(SHB + 73728);
    int*   segoff = hist + 256;
    int*   cursor = segoff + 256;
    int*   gbase  = cursor + 256;
    int*   sc     = gbase + 256;
    int e0 = bid * CHUNK;
    int m = min(E - e0, CHUNK);
    for (int i = tid; i < m; i += 256) {
        unsigned d = (unsigned)edst[e0 + i];
        unsigned s = (unsigned)esrc[e0 + i];
        payL[i] = s | ((d & (BSZ - 1)) << 23);
        bktL[i] = (uchar)(d >> BSH);
    }
    hist[tid] = 0;
    __syncthreads();
    for (int i = tid; i < m; i += 256)
        atomicAdd(&hist[bktL[i]], 1);
    __syncthreads();
    sc[tid] = hist[tid];
    __syncthreads();
    for (int off = 1; off < 256; off <<= 1) {
        int v = (tid >= off) ? sc[tid - off] : 0;
        __syncthreads();
        sc[tid] += v;
        __syncthreads();
    }
    segoff[tid] = sc[tid] - hist[tid];
    cursor[tid] = segoff[tid];
    if (tid < nb && hist[tid] > 0) gbase[tid] = atomicAdd(&bucketCursor[tid], hist[tid]);
    __syncthreads();
    for (int i = tid; i < m; i += 256) {
        int b = (int)bktL[i];
        int p = atomicAdd(&cursor[b], 1);
        outL[p] = payL[i];
    }
    __syncthreads();
    int wave = tid >> 6, lane = tid & 63;
    for (int b = wave; b < nb; b += 4) {
        int off = segoff[b], len = hist[b];
        if (len == 0) continue;
        int gb = gbase[b];
        unsigned* dst = gSorted + (size_t)b * BCAP;
        for (int i = lane; i < len; i += 64)
            if (gb + i < BCAP) dst[gb + i] = outL[off + i];
    }
}

// ---------- p4_build: quarter-bucket ELL build (128 nodes, 32KB LDS -> 4 blocks/CU) ----------
__global__ __launch_bounds__(256) void p4_build(const unsigned* __restrict__ gSorted,
                                                const int* __restrict__ bucketCursor,
                                                int nb, int N, int* __restrict__ cnt,
                                                float* __restrict__ isd,
                                                int* __restrict__ ell) {
    __shared__ unsigned ellL[128 * CAPD];  // 32KB
    __shared__ int cntL[128];
    int bid = blockIdx.x, tid = threadIdx.x;
    int bucket = bid >> 2;
    unsigned sub = (unsigned)(bid & 3);
    int n0 = bid * 128;
    int nValid = min(128, N - n0);
    if (nValid <= 0) return;
    for (int i = tid; i < 128; i += 256) cntL[i] = 0;
    __syncthreads();
    int len = bucketCursor[bucket];
    if (len > BCAP) len = BCAP;
    const unsigned* seg = gSorted + (size_t)bucket * BCAP;
    for (int i = tid; i < len; i += 256) {
        unsigned e = seg[i];
        unsigned dl = e >> 23;
        if ((dl >> 7) == sub) {
            int r = (int)(dl & 127u);
            int p = atomicAdd(&cntL[r], 1);
            if (p < CAPD) ellL[r * CAPD + p] = e & 0x7FFFFFu;
        }
    }
    __syncthreads();
    int total = nValid * CAPD;
    const int* ellLi = (const int*)ellL;
    for (int i = tid; i < total; i += 256) {
        int row = i >> 6, pos = i & 63;
        int c = cntL[row];
        if (pos < min(c, CAPD))
            ell[(size_t)n0 * CAPD + i] = ellLi[i];
    }
    for (int i = tid; i < nValid; i += 256) {
        int c = cntL[i];
        cnt[n0 + i] = c;
        isd[n0 + i] = rsqrtf(1.0f + (float)c);
    }
}

// ---------- shared GEMM core: fp16 MFMA, biased-uint8 quantized output ----------
// Tq[node][128] biased-u8 (32 words); Ts[node] = rowmax/127 (after optional `scale`).
// If TscOut != nullptr: TscOut[node] = Ts[node] * isdT[node] (fused tsc).
__device__ __forceinline__ void gemm_core(const void* __restrict__ A, int aF16,
                                          const uint* __restrict__ Wt,
                                          const float* __restrict__ scale,   // nullptr -> 1
                                          const float* __restrict__ isdT,    // for TscOut
                                          uint* __restrict__ Tq,
                                          float* __restrict__ Ts,
                                          float* __restrict__ TscOut,        // may be nullptr
                                          int n, int m0, int tid, uint* SH) {
    char* shb = (char*)SH;
    if (aF16) {
        const uint* Af = (const uint*)A;
#pragma unroll
        for (int j = 0; j < 8; ++j) {
            int q = tid + 256 * j;
            int row = q >> 4, c16 = q & 15;
            int grow = m0 + row;
            uint4 v = make_uint4(0u, 0u, 0u, 0u);
            if (grow < n) v = *reinterpret_cast<const uint4*>(Af + (size_t)grow * 64 + c16 * 4);
            *reinterpret_cast<uint4*>(shb + row * 256 + ((c16 * 16) ^ ((row & 7) << 4))) = v;
        }
    } else {
        const float* Af = (const float*)A;
#pragma unroll
        for (int j = 0; j < 8; ++j) {
            int q = tid + 256 * j;
            int row = q >> 4, c16 = q & 15;
            int grow = m0 + row;
            uint4 o = make_uint4(0u, 0u, 0u, 0u);
            if (grow < n) {
                float4 v0 = *reinterpret_cast<const float4*>(Af + (size_t)grow * 128 + c16 * 8);
                float4 v1 = *reinterpret_cast<const float4*>(Af + (size_t)grow * 128 + c16 * 8 + 4);
                o.x = h_pack(v0.x, v0.y); o.y = h_pack(v0.z, v0.w);
                o.z = h_pack(v1.x, v1.y); o.w = h_pack(v1.z, v1.w);
            }
            *reinterpret_cast<uint4*>(shb + row * 256 + ((c16 * 16) ^ ((row & 7) << 4))) = o;
        }
    }
#pragma unroll
    for (int j = 0; j < 8; ++j) {
        int q = tid + 256 * j;
        int col = q >> 4, c16 = q & 15;
        uint4 v = *reinterpret_cast<const uint4*>(Wt + col * 64 + c16 * 4);
        *reinterpret_cast<uint4*>(shb + 32768 + col * 256 + ((c16 * 16) ^ ((col & 7) << 4))) = v;
    }
    __syncthreads();

    const int w = tid >> 6, l = tid & 63;
    const int lrow = l & 15, kg = l >> 4;
    const int swz = (lrow & 7) << 4;

    f32x4 acc[2][8] = {};
#pragma unroll
    for (int kk = 0; kk < 4; ++kk) {
        const int koff = (kk * 64 + kg * 16) ^ swz;
        f16x8 a[2], b[8];
#pragma unroll
        for (int mr = 0; mr < 2; ++mr) {
            int r = w * 32 + mr * 16 + lrow;
            a[mr] = *reinterpret_cast<const f16x8*>(shb + r * 256 + koff);
        }
#pragma unroll
        for (int nc = 0; nc < 8; ++nc) {
            int c = nc * 16 + lrow;
            b[nc] = *reinterpret_cast<const f16x8*>(shb + 32768 + c * 256 + koff);
        }
#pragma unroll
        for (int mr = 0; mr < 2; ++mr)
#pragma unroll
            for (int nc = 0; nc < 8; ++nc)
                acc[mr][nc] = __builtin_amdgcn_mfma_f32_16x16x32_f16(a[mr], b[nc], acc[mr][nc], 0, 0, 0);
    }
    __syncthreads();

    // C/D layout (m89): col = lane&15, row = (lane>>4)*4 + reg.
    ushort* Cs = (ushort*)SH;   // [128][136]
#pragma unroll
    for (int mr = 0; mr < 2; ++mr) {
        int rb = w * 32 + mr * 16 + kg * 4;
#pragma unroll
        for (int i = 0; i < 4; ++i) {
            int grow = m0 + rb + i;
            float s = scale ? ((grow < n) ? scale[grow] : 0.f) : 1.f;
#pragma unroll
            for (int nc = 0; nc < 8; ++nc)
                Cs[(rb + i) * 136 + nc * 16 + lrow] = h_bits(s * acc[mr][nc][i]);
        }
    }
    __syncthreads();
    const uint* Cw = (const uint*)SH;             // stride 68 words/row
#pragma unroll
    for (int j = 0; j < 8; ++j) {
        int q = tid + 256 * j;
        int row = q >> 4, c8 = q & 15;
        int grow = m0 + row;
        uint4 v = *reinterpret_cast<const uint4*>(Cw + row * 68 + c8 * 4);
        float f0 = h_lo(v.x), f1 = h_hi(v.x), f2 = h_lo(v.y), f3 = h_hi(v.y);
        float f4 = h_lo(v.z), f5 = h_hi(v.z), f6 = h_lo(v.w), f7 = h_hi(v.w);
        float mx = fmaxf(fmaxf(fmaxf(fabsf(f0), fabsf(f1)), fmaxf(fabsf(f2), fabsf(f3))),
                         fmaxf(fmaxf(fabsf(f4), fabsf(f5)), fmaxf(fabsf(f6), fabsf(f7))));
#pragma unroll
        for (int off = 8; off > 0; off >>= 1) mx = fmaxf(mx, __shfl_xor(mx, off, 16));
        mx = fmaxf(mx, 1e-20f);
        float inv = 127.f / mx;
        int q0 = (int)rintf(f0 * inv) + 128, q1 = (int)rintf(f1 * inv) + 128;
        int q2 = (int)rintf(f2 * inv) + 128, q3 = (int)rintf(f3 * inv) + 128;
        int q4 = (int)rintf(f4 * inv) + 128, q5 = (int)rintf(f5 * inv) + 128;
        int q6 = (int)rintf(f6 * inv) + 128, q7 = (int)rintf(f7 * inv) + 128;
        uint w0 = (uint)q0 | ((uint)q1 << 8) | ((uint)q2 << 16) | ((uint)q3 << 24);
        uint w1 = (uint)q4 | ((uint)q5 << 8) | ((uint)q6 << 16) | ((uint)q7 << 24);
        if (grow < n) {
            *reinterpret_cast<uint2*>(Tq + (size_t)grow * 32 + c8 * 2) = make_uint2(w0, w1);
            if (c8 == 0) {
                float ts = mx * (1.f / 127.f);
                Ts[grow] = ts;
                if (TscOut) TscOut[grow] = ts * isdT[grow];
            }
        }
    }
}

// ---------- layer-1 GEMM (unscaled; writes Ts and Tsc = Ts*isd) ----------
__global__ __launch_bounds__(256) void gemm1_kernel(const float* __restrict__ x,
                                                    const uint* __restrict__ Wt,
                                                    const float* __restrict__ isd,
                                                    uint* __restrict__ Tq,
                                                    float* __restrict__ Ts,
                                                    float* __restrict__ Tsc, int n) {
    __shared__ __align__(16) uint SH[16384];
    gemm_core(x, 0, Wt, nullptr, isd, Tq, Ts, Tsc, n, blockIdx.x * 128, threadIdx.x, SH);
}

// ---------- layer-2 GEMM (isd scale in epilogue) ----------
__global__ __launch_bounds__(256) void gemm2_kernel(const uint* __restrict__ Hb,
                                                    const uint* __restrict__ Wt,
                                                    const float* __restrict__ isd,
                                                    uint* __restrict__ Tq,
                                                    float* __restrict__ Ts, int n) {
    __shared__ __align__(16) uint SH[16384];
    gemm_core(Hb, 1, Wt, isd, nullptr, Tq, Ts, nullptr, n, blockIdx.x * 128, threadIdx.x, SH);
}

// ---------- agg layer 1: single scale array Tsc = Ts*isd. Half-wave per node. ----------
// a_dim = sum Tsc_j*u - 128*sum Tsc_j ; H = fp16(relu(isd_i*a + bias))
__global__ __launch_bounds__(256) void agg_kernel(const uint* __restrict__ Tq,
                                                  const float* __restrict__ Tsc,
                                                  const int* __restrict__ ell,
                                                  const int* __restrict__ cnt,
                                                  const float* __restrict__ isd,
                                                  const float* __restrict__ bias,
                                                  uint* __restrict__ Hb, int n) {
    int node = (int)((blockIdx.x * 256 + threadIdx.x) >> 5);
    int ln = threadIdx.x & 31;
    if (node >= n) return;
    float di = isd[node];
    int c = cnt[node];
    if (c > CAPD) c = CAPD;
    const int* row = ell + (size_t)node * CAPD;
    float a0, a1, a2, a3, ssum;
    {
        uint v = Tq[(size_t)node * 32 + ln];
        float sc = Tsc[node];
        ssum = sc;
        a0 = sc * ub0(v); a1 = sc * ub1(v); a2 = sc * ub2(v); a3 = sc * ub3(v);
    }
    int j = 0;
    for (; j + 8 <= c; j += 8) {
        int4 sa = *reinterpret_cast<const int4*>(row + j);
        int4 sb = *reinterpret_cast<const int4*>(row + j + 4);
        uint v0 = Tq[(size_t)sa.x * 32 + ln]; float c0 = Tsc[sa.x];
        uint v1 = Tq[(size_t)sa.y * 32 + ln]; float c1 = Tsc[sa.y];
        uint v2 = Tq[(size_t)sa.z * 32 + ln]; float c2 = Tsc[sa.z];
        uint v3 = Tq[(size_t)sa.w * 32 + ln]; float c3 = Tsc[sa.w];
        uint v4 = Tq[(size_t)sb.x * 32 + ln]; float c4 = Tsc[sb.x];
        uint v5 = Tq[(size_t)sb.y * 32 + ln]; float c5 = Tsc[sb.y];
        uint v6 = Tq[(size_t)sb.z * 32 + ln]; float c6 = Tsc[sb.z];
        uint v7 = Tq[(size_t)sb.w * 32 + ln]; float c7 = Tsc[sb.w];
        ssum += ((c0 + c1) + (c2 + c3)) + ((c4 + c5) + (c6 + c7));
        a0 = fmaf(c0, ub0(v0), fmaf(c1, ub0(v1), fmaf(c2, ub0(v2), fmaf(c3, ub0(v3),
             fmaf(c4, ub0(v4), fmaf(c5, ub0(v5), fmaf(c6, ub0(v6), fmaf(c7, ub0(v7), a0))))))));
        a1 = fmaf(c0, ub1(v0), fmaf(c1, ub1(v1), fmaf(c2, ub1(v2), fmaf(c3, ub1(v3),
             fmaf(c4, ub1(v4), fmaf(c5, ub1(v5), fmaf(c6, ub1(v6), fmaf(c7, ub1(v7), a1))))))));
        a2 = fmaf(c0, ub2(v0), fmaf(c1, ub2(v1), fmaf(c2, ub2(v2), fmaf(c3, ub2(v3),
             fmaf(c4, ub2(v4), fmaf(c5, ub2(v5), fmaf(c6, ub2(v6), fmaf(c7, ub2(v7), a2))))))));
        a3 = fmaf(c0, ub3(v0), fmaf(c1, ub3(v1), fmaf(c2, ub3(v2), fmaf(c3, ub3(v3),
             fmaf(c4, ub3(v4), fmaf(c5, ub3(v5), fmaf(c6, ub3(v6), fmaf(c7, ub3(v7), a3))))))));
    }
    for (; j + 4 <= c; j += 4) {
        int4 s4 = *reinterpret_cast<const int4*>(row + j);
        uint v0 = Tq[(size_t)s4.x * 32 + ln]; float c0 = Tsc[s4.x];
        uint v1 = Tq[(size_t)s4.y * 32 + ln]; float c1 = Tsc[s4.y];
        uint v2 = Tq[(size_t)s4.z * 32 + ln]; float c2 = Tsc[s4.z];
        uint v3 = Tq[(size_t)s4.w * 32 + ln]; float c3 = Tsc[s4.w];
        ssum += (c0 + c1) + (c2 + c3);
        a0 = fmaf(c0, ub0(v0), fmaf(c1, ub0(v1), fmaf(c2, ub0(v2), fmaf(c3, ub0(v3), a0))));
        a1 = fmaf(c0, ub1(v0), fmaf(c1, ub1(v1), fmaf(c2, ub1(v2), fmaf(c3, ub1(v3), a1))));
        a2 = fmaf(c0, ub2(v0), fmaf(c1, ub2(v1), fmaf(c2, ub2(v2), fmaf(c3, ub2(v3), a2))));
        a3 = fmaf(c0, ub3(v0), fmaf(c1, ub3(v1), fmaf(c2, ub3(v2), fmaf(c3, ub3(v3), a3))));
    }
    for (; j < c; ++j) {
        int s = row[j];
        uint v = Tq[(size_t)s * 32 + ln];
        float sc = Tsc[s];
        ssum += sc;
        a0 = fmaf(sc, ub0(v), a0); a1 = fmaf(sc, ub1(v), a1);
        a2 = fmaf(sc, ub2(v), a2); a3 = fmaf(sc, ub3(v), a3);
    }
    float off = 128.f * ssum;
    float4 bv = *reinterpret_cast<const float4*>(bias + ln * 4);
    float h0 = fmaxf(fmaf(di, a0 - off, bv.x), 0.f);
    float h1 = fmaxf(fmaf(di, a1 - off, bv.y), 0.f);
    float h2 = fmaxf(fmaf(di, a2 - off, bv.z), 0.f);
    float h3 = fmaxf(fmaf(di, a3 - off, bv.w), 0.f);
    *reinterpret_cast<uint2*>(Hb + (size_t)node * 64 + ln * 2) =
        make_uint2(h_pack(h0, h1), h_pack(h2, h3));
}

// ---------- agg layer 2 + head: sc_j = Ts[j] (isd already in Tq scale) ----------
__global__ __launch_bounds__(256) void agg_out_kernel(const uint* __restrict__ Tq,
                                                      const float* __restrict__ Ts,
                                                      const int* __restrict__ ell,
                                                      const int* __restrict__ cnt,
                                                      const float* __restrict__ isd,
                                                      const float* __restrict__ bias,
                                                      const float* __restrict__ Wout,
                                                      const float* __restrict__ bout,
                                                      float* __restrict__ out, int n) {
    int node = (int)((blockIdx.x * 256 + threadIdx.x) >> 5);
    int ln = threadIdx.x & 31;
    if (node >= n) return;
    float di = isd[node];
    int c = cnt[node];
    if (c > CAPD) c = CAPD;
    const int* row = ell + (size_t)node * CAPD;
    float a0, a1, a2, a3, ssum;
    {
        uint v = Tq[(size_t)node * 32 + ln];
        float sc = Ts[node];
        ssum = sc;
        a0 = sc * ub0(v); a1 = sc * ub1(v); a2 = sc * ub2(v); a3 = sc * ub3(v);
    }
    int j = 0;
    for (; j + 8 <= c; j += 8) {
        int4 sa = *reinterpret_cast<const int4*>(row + j);
        int4 sb = *reinterpret_cast<const int4*>(row + j + 4);
        uint v0 = Tq[(size_t)sa.x * 32 + ln]; float c0 = Ts[sa.x];
        uint v1 = Tq[(size_t)sa.y * 32 + ln]; float c1 = Ts[sa.y];
        uint v2 = Tq[(size_t)sa.z * 32 + ln]; float c2 = Ts[sa.z];
        uint v3 = Tq[(size_t)sa.w * 32 + ln]; float c3 = Ts[sa.w];
        uint v4 = Tq[(size_t)sb.x * 32 + ln]; float c4 = Ts[sb.x];
        uint v5 = Tq[(size_t)sb.y * 32 + ln]; float c5 = Ts[sb.y];
        uint v6 = Tq[(size_t)sb.z * 32 + ln]; float c6 = Ts[sb.z];
        uint v7 = Tq[(size_t)sb.w * 32 + ln]; float c7 = Ts[sb.w];
        ssum += ((c0 + c1) + (c2 + c3)) + ((c4 + c5) + (c6 + c7));
        a0 = fmaf(c0, ub0(v0), fmaf(c1, ub0(v1), fmaf(c2, ub0(v2), fmaf(c3, ub0(v3),
             fmaf(c4, ub0(v4), fmaf(c5, ub0(v5), fmaf(c6, ub0(v6), fmaf(c7, ub0(v7), a0))))))));
        a1 = fmaf(c0, ub1(v0), fmaf(c1, ub1(v1), fmaf(c2, ub1(v2), fmaf(c3, ub1(v3),
             fmaf(c4, ub1(v4), fmaf(c5, ub1(v5), fmaf(c6, ub1(v6), fmaf(c7, ub1(v7), a1))))))));
        a2 = fmaf(c0, ub2(v0), fmaf(c1, ub2(v1), fmaf(c2, ub2(v2), fmaf(c3, ub2(v3),
             fmaf(c4, ub2(v4), fmaf(c5, ub2(v5), fmaf(c6, ub2(v6), fmaf(c7, ub2(v7), a2))))))));
        a3 = fmaf(c0, ub3(v0), fmaf(c1, ub3(v1), fmaf(c2, ub3(v2), fmaf(c3, ub3(v3),
             fmaf(c4, ub3(v4), fmaf(c5, ub3(v5), fmaf(c6, ub3(v6), fmaf(c7, ub3(v7), a3))))))));
    }
    for (; j + 4 <= c; j += 4) {
        int4 s4 = *reinterpret_cast<const int4*>(row + j);
        uint v0 = Tq[(size_t)s4.x * 32 + ln]; float c0 = Ts[s4.x];
        uint v1 = Tq[(size_t)s4.y * 32 + ln]; float c1 = Ts[s4.y];
        uint v2 = Tq[(size_t)s4.z * 32 + ln]; float c2 = Ts[s4.z];
        uint v3 = Tq[(size_t)s4.w * 32 + ln]; float c3 = Ts[s4.w];
        ssum += (c0 + c1) + (c2 + c3);
        a0 = fmaf(c0, ub0(v0), fmaf(c1, ub0(v1), fmaf(c2, ub0(v2), fmaf(c3, ub0(v3), a0))));
        a1 = fmaf(c0, ub1(v0), fmaf(c1, ub1(v1), fmaf(c2, ub1(v2), fmaf(c3, ub1(v3), a1))));
        a2 = fmaf(c0, ub2(v0), fmaf(c1, ub2(v1), fmaf(c2, ub2(v2), fmaf(c3, ub2(v3), a2))));
        a3 = fmaf(c0, ub3(v0), fmaf(c1, ub3(v1), fmaf(c2, ub3(v2), fmaf(c3, ub3(v3), a3))));
    }
    for (; j < c; ++j) {
        int s = row[j];
        uint v = Tq[(size_t)s * 32 + ln];
        float sc = Ts[s];
        ssum += sc;
        a0 = fmaf(sc, ub0(v), a0); a1 = fmaf(sc, ub1(v), a1);
        a2 = fmaf(sc, ub2(v), a2); a3 = fmaf(sc, ub3(v), a3);
    }
    float off = 128.f * ssum;
    float4 bv = *reinterpret_cast<const float4*>(bias + ln * 4);
    float4 wv = *reinterpret_cast<const float4*>(Wout + ln * 4);
    float h0 = fmaxf(fmaf(di, a0 - off, bv.x), 0.f);
    float h1 = fmaxf(fmaf(di, a1 - off, bv.y), 0.f);
    float h2 = fmaxf(fmaf(di, a2 - off, bv.z), 0.f);
    float h3 = fmaxf(fmaf(di, a3 - off, bv.w), 0.f);
    float v = fmaf(h0, wv.x, fmaf(h1, wv.y, fmaf(h2, wv.z, h3 * wv.w)));
#pragma unroll
    for (int off2 = 16; off2 > 0; off2 >>= 1) v += __shfl_xor(v, off2, 32);
    if (ln == 0) out[node] = 1.f / (1.f + expf(-(v + bout[0])));
}

extern "C" void kernel_launch(void* const* d_in, const int* in_sizes, int n_in,
                              void* d_out, int out_size, void* d_ws, size_t ws_size,
                              hipStream_t stream) {
    const float* x    = (const float*)d_in[0];
    const int*   ei   = (const int*)d_in[1];
    const float* W1   = (const float*)d_in[2];
    const float* b1   = (const float*)d_in[3];
    const float* W2   = (const float*)d_in[4];
    const float* b2   = (const float*)d_in[5];
    const float* Wout = (const float*)d_in[6];
    const float* bout = (const float*)d_in[7];
    float* out = (float*)d_out;

    const int N = in_sizes[0] / 128;
    const int E = in_sizes[1] / 2;
    const int* esrc = ei;
    const int* edst = ei + E;

    char* p = (char*)d_ws;
    auto alloc = [&](size_t bytes) {
        char* r = p;
        p += (bytes + 255) & ~(size_t)255;
        return (void*)r;
    };
    const int nb  = (N + BSZ - 1) / BSZ;       // p3 buckets (<=256)
    const int NB2 = (E + CHUNK - 1) / CHUNK;   // partition blocks

    int*   cnt = (int*)  alloc((size_t)N * 4);
    float* isd = (float*)alloc((size_t)N * 4);
    int*   ell = (int*)  alloc((size_t)N * CAPD * 4);
    uint*  Tq  = (uint*) alloc((size_t)N * 32 * 4);   // biased-u8 rows, 128 B/node
    float* Ts  = (float*)alloc((size_t)(N + 4) * 4);  // per-row scales
    float* Tsc = (float*)alloc((size_t)(N + 4) * 4);  // Ts*isd (layer-1 agg)
    uint*  Hb  = (uint*) alloc((size_t)N * 64 * 4);   // hidden, fp16 pairs
    uint*  Wt1 = (uint*) alloc(8192 * 4);
    uint*  Wt2 = (uint*) alloc(8192 * 4);
    unsigned* gSorted      = (unsigned*)alloc((size_t)nb * BCAP * 4);
    int*      bucketCursor = (int*)     alloc((size_t)nb * 4);

    hipMemsetAsync(bucketCursor, 0, (size_t)nb * 4, stream);
    p3_scatter<<<NB2 + 2, 256, 0, stream>>>(esrc, edst, E, nb, NB2, bucketCursor, gSorted,
                                            W1, W2, Wt1, Wt2);
    // ELL build: quarter-buckets (128 nodes/block, 32KB LDS -> 4 blocks/CU)
    p4_build<<<4 * nb, 256, 0, stream>>>(gSorted, bucketCursor, nb, N, cnt, isd, ell);

    const int gblocks = (N + 127) / 128;
    const int ablocks = (N + 7) / 8;   // one node per half-wave
    // Layer 1 GEMM (unscaled; writes Ts and Tsc = Ts*isd — tsc fused here)
    gemm1_kernel<<<gblocks, 256, 0, stream>>>(x, Wt1, isd, Tq, Ts, Tsc, N);
    // Layer-1 agg
    agg_kernel<<<ablocks, 256, 0, stream>>>(Tq, Tsc, ell, cnt, isd, b1, Hb, N);
    // Layer-2 GEMM (isd scale in epilogue)
    gemm2_kernel<<<gblocks, 256, 0, stream>>>(Hb, Wt2, isd, Tq, Ts, N);
    // Layer-2 agg + head
    agg_out_kernel<<<ablocks, 256, 0, stream>>>(Tq, Ts, ell, cnt, isd, b2, Wout, bout, out, N);
}

// Round 18
// 166.326 us; speedup vs baseline: 1.1330x; 1.1330x over previous
//
#include <hip/hip_runtime.h>
#include <cstddef>

#define CAPD 64
#define BSZ 512        // nodes per bucket (p3 granularity)
#define BSH 9          // log2(BSZ)
#define CHUNK 8192     // edges per partition block
#define BCAP 12288     // per-bucket edge capacity (mean 8163, sigma ~90 -> safe)

typedef unsigned int uint;
typedef unsigned short ushort;
typedef unsigned char uchar;
typedef float f32x4 __attribute__((ext_vector_type(4)));
typedef _Float16 f16x8 __attribute__((ext_vector_type(8)));  // 8 fp16 = 4 VGPRs

// fp16 helpers: word = dimEven | dimOdd<<16
__device__ inline float h_lo(uint v) {
    union { ushort u; _Float16 h; } c; c.u = (ushort)(v & 0xFFFFu); return (float)c.h;
}
__device__ inline float h_hi(uint v) {
    union { ushort u; _Float16 h; } c; c.u = (ushort)(v >> 16); return (float)c.h;
}
__device__ inline ushort h_bits(float x) {
    union { _Float16 h; ushort u; } c; c.h = (_Float16)x; return c.u;
}
__device__ inline uint h_pack(float a, float b) {
    return (uint)h_bits(a) | ((uint)h_bits(b) << 16);
}
// biased-uint8 byte k -> float (maps to v_cvt_f32_ubyte[k])
__device__ inline float ub0(uint v) { return (float)(v & 0xFFu); }
__device__ inline float ub1(uint v) { return (float)((v >> 8) & 0xFFu); }
__device__ inline float ub2(uint v) { return (float)((v >> 16) & 0xFFu); }
__device__ inline float ub3(uint v) { return (float)(v >> 24); }

// ---------- prep: block 0 zeros bucketCursor; blocks 1,2 transpose W1,W2 ----------
__global__ __launch_bounds__(256) void prep_kernel(int* __restrict__ bucketCursor, int nb,
                                                   const float* __restrict__ W1,
                                                   const float* __restrict__ W2,
                                                   uint* __restrict__ Wt1,
                                                   uint* __restrict__ Wt2) {
    __shared__ float ws[128][129];
    int bid = blockIdx.x, tid = threadIdx.x;
    if (bid == 0) {
        for (int i = tid; i < nb; i += 256) bucketCursor[i] = 0;
        return;
    }
    const float* W = (bid == 2) ? W2 : W1;
    uint* O = (bid == 2) ? Wt2 : Wt1;
#pragma unroll
    for (int j = 0; j < 16; ++j) {
        int q = tid + 256 * j;
        int k = q >> 5, c = (q & 31) * 4;
        float4 v = *reinterpret_cast<const float4*>(W + k * 128 + c);
        ws[k][c] = v.x; ws[k][c + 1] = v.y; ws[k][c + 2] = v.z; ws[k][c + 3] = v.w;
    }
    __syncthreads();
#pragma unroll
    for (int j = 0; j < 32; ++j) {
        int q = tid + 256 * j;
        int ncol = q >> 6, kw = q & 63;
        O[q] = h_pack(ws[2 * kw][ncol], ws[2 * kw + 1][ncol]);
    }
}

// ---------- shared GEMM core: fp16 MFMA, biased-uint8 quantized output ----------
// Tq[node][128] biased-u8 (32 words); Ts[node] = rowmax/127 (after optional `scale`).
__device__ __forceinline__ void gemm_core(const void* __restrict__ A, int aF16,
                                          const uint* __restrict__ Wt,
                                          const float* __restrict__ scale,   // nullptr -> 1
                                          uint* __restrict__ Tq,
                                          float* __restrict__ Ts,
                                          int n, int m0, int tid, uint* SH) {
    char* shb = (char*)SH;
    if (aF16) {
        const uint* Af = (const uint*)A;
#pragma unroll
        for (int j = 0; j < 8; ++j) {
            int q = tid + 256 * j;
            int row = q >> 4, c16 = q & 15;
            int grow = m0 + row;
            uint4 v = make_uint4(0u, 0u, 0u, 0u);
            if (grow < n) v = *reinterpret_cast<const uint4*>(Af + (size_t)grow * 64 + c16 * 4);
            *reinterpret_cast<uint4*>(shb + row * 256 + ((c16 * 16) ^ ((row & 7) << 4))) = v;
        }
    } else {
        const float* Af = (const float*)A;
#pragma unroll
        for (int j = 0; j < 8; ++j) {
            int q = tid + 256 * j;
            int row = q >> 4, c16 = q & 15;
            int grow = m0 + row;
            uint4 o = make_uint4(0u, 0u, 0u, 0u);
            if (grow < n) {
                float4 v0 = *reinterpret_cast<const float4*>(Af + (size_t)grow * 128 + c16 * 8);
                float4 v1 = *reinterpret_cast<const float4*>(Af + (size_t)grow * 128 + c16 * 8 + 4);
                o.x = h_pack(v0.x, v0.y); o.y = h_pack(v0.z, v0.w);
                o.z = h_pack(v1.x, v1.y); o.w = h_pack(v1.z, v1.w);
            }
            *reinterpret_cast<uint4*>(shb + row * 256 + ((c16 * 16) ^ ((row & 7) << 4))) = o;
        }
    }
#pragma unroll
    for (int j = 0; j < 8; ++j) {
        int q = tid + 256 * j;
        int col = q >> 4, c16 = q & 15;
        uint4 v = *reinterpret_cast<const uint4*>(Wt + col * 64 + c16 * 4);
        *reinterpret_cast<uint4*>(shb + 32768 + col * 256 + ((c16 * 16) ^ ((col & 7) << 4))) = v;
    }
    __syncthreads();

    const int w = tid >> 6, l = tid & 63;
    const int lrow = l & 15, kg = l >> 4;
    const int swz = (lrow & 7) << 4;

    f32x4 acc[2][8] = {};
#pragma unroll
    for (int kk = 0; kk < 4; ++kk) {
        const int koff = (kk * 64 + kg * 16) ^ swz;
        f16x8 a[2], b[8];
#pragma unroll
        for (int mr = 0; mr < 2; ++mr) {
            int r = w * 32 + mr * 16 + lrow;
            a[mr] = *reinterpret_cast<const f16x8*>(shb + r * 256 + koff);
        }
#pragma unroll
        for (int nc = 0; nc < 8; ++nc) {
            int c = nc * 16 + lrow;
            b[nc] = *reinterpret_cast<const f16x8*>(shb + 32768 + c * 256 + koff);
        }
#pragma unroll
        for (int mr = 0; mr < 2; ++mr)
#pragma unroll
            for (int nc = 0; nc < 8; ++nc)
                acc[mr][nc] = __builtin_amdgcn_mfma_f32_16x16x32_f16(a[mr], b[nc], acc[mr][nc], 0, 0, 0);
    }
    __syncthreads();

    // C/D layout (m89): col = lane&15, row = (lane>>4)*4 + reg.
    ushort* Cs = (ushort*)SH;   // [128][136]
#pragma unroll
    for (int mr = 0; mr < 2; ++mr) {
        int rb = w * 32 + mr * 16 + kg * 4;
#pragma unroll
        for (int i = 0; i < 4; ++i) {
            int grow = m0 + rb + i;
            float s = scale ? ((grow < n) ? scale[grow] : 0.f) : 1.f;
#pragma unroll
            for (int nc = 0; nc < 8; ++nc)
                Cs[(rb + i) * 136 + nc * 16 + lrow] = h_bits(s * acc[mr][nc][i]);
        }
    }
    __syncthreads();
    const uint* Cw = (const uint*)SH;             // stride 68 words/row
#pragma unroll
    for (int j = 0; j < 8; ++j) {
        int q = tid + 256 * j;
        int row = q >> 4, c8 = q & 15;
        int grow = m0 + row;
        uint4 v = *reinterpret_cast<const uint4*>(Cw + row * 68 + c8 * 4);
        float f0 = h_lo(v.x), f1 = h_hi(v.x), f2 = h_lo(v.y), f3 = h_hi(v.y);
        float f4 = h_lo(v.z), f5 = h_hi(v.z), f6 = h_lo(v.w), f7 = h_hi(v.w);
        float mx = fmaxf(fmaxf(fmaxf(fabsf(f0), fabsf(f1)), fmaxf(fabsf(f2), fabsf(f3))),
                         fmaxf(fmaxf(fabsf(f4), fabsf(f5)), fmaxf(fabsf(f6), fabsf(f7))));
#pragma unroll
        for (int off = 8; off > 0; off >>= 1) mx = fmaxf(mx, __shfl_xor(mx, off, 16));
        mx = fmaxf(mx, 1e-20f);
        float inv = 127.f / mx;
        int q0 = (int)rintf(f0 * inv) + 128, q1 = (int)rintf(f1 * inv) + 128;
        int q2 = (int)rintf(f2 * inv) + 128, q3 = (int)rintf(f3 * inv) + 128;
        int q4 = (int)rintf(f4 * inv) + 128, q5 = (int)rintf(f5 * inv) + 128;
        int q6 = (int)rintf(f6 * inv) + 128, q7 = (int)rintf(f7 * inv) + 128;
        uint w0 = (uint)q0 | ((uint)q1 << 8) | ((uint)q2 << 16) | ((uint)q3 << 24);
        uint w1 = (uint)q4 | ((uint)q5 << 8) | ((uint)q6 << 16) | ((uint)q7 << 24);
        if (grow < n) {
            *reinterpret_cast<uint2*>(Tq + (size_t)grow * 32 + c8 * 2) = make_uint2(w0, w1);
            if (c8 == 0) Ts[grow] = mx * (1.f / 127.f);
        }
    }
}

// ---------- p3gemm1: blocks [0,NB2) partition; rest run layer-1 GEMM (overlapped) ----------
__global__ __launch_bounds__(256) void p3gemm1(const int* __restrict__ esrc,
                                               const int* __restrict__ edst, int E,
                                               int nb, int NB2,
                                               int* __restrict__ bucketCursor,
                                               unsigned* __restrict__ gSorted,
                                               const float* __restrict__ x,
                                               const uint* __restrict__ Wt1,
                                               uint* __restrict__ Tq,
                                               float* __restrict__ Ts, int N) {
    __shared__ __align__(16) char SHB[78848];  // 77KB (union of both paths)
    int bid = blockIdx.x, tid = threadIdx.x;
    if (bid >= NB2) {
        // layer-1 GEMM, unscaled (Tsc derived in p4_build)
        gemm_core(x, 0, Wt1, nullptr, Tq, Ts, N, (bid - NB2) * 128, tid, (uint*)SHB);
        return;
    }
    uint*  payL = (uint*)SHB;                 // 32KB
    uint*  outL = (uint*)(SHB + 32768);       // 32KB
    uchar* bktL = (uchar*)(SHB + 65536);      // 8KB
    int*   hist   = (int*)(SHB + 73728);
    int*   segoff = hist + 256;
    int*   cursor = segoff + 256;
    int*   gbase  = cursor + 256;
    int*   sc     = gbase + 256;
    int e0 = bid * CHUNK;
    int m = min(E - e0, CHUNK);
    for (int i = tid; i < m; i += 256) {
        unsigned d = (unsigned)edst[e0 + i];
        unsigned s = (unsigned)esrc[e0 + i];
        payL[i] = s | ((d & (BSZ - 1)) << 23);
        bktL[i] = (uchar)(d >> BSH);
    }
    hist[tid] = 0;
    __syncthreads();
    for (int i = tid; i < m; i += 256)
        atomicAdd(&hist[bktL[i]], 1);
    __syncthreads();
    sc[tid] = hist[tid];
    __syncthreads();
    for (int off = 1; off < 256; off <<= 1) {
        int v = (tid >= off) ? sc[tid - off] : 0;
        __syncthreads();
        sc[tid] += v;
        __syncthreads();
    }
    segoff[tid] = sc[tid] - hist[tid];
    cursor[tid] = segoff[tid];
    if (tid < nb && hist[tid] > 0) gbase[tid] = atomicAdd(&bucketCursor[tid], hist[tid]);
    __syncthreads();
    for (int i = tid; i < m; i += 256) {
        int b = (int)bktL[i];
        int p = atomicAdd(&cursor[b], 1);
        outL[p] = payL[i];
    }
    __syncthreads();
    int wave = tid >> 6, lane = tid & 63;
    for (int b = wave; b < nb; b += 4) {
        int off = segoff[b], len = hist[b];
        if (len == 0) continue;
        int gb = gbase[b];
        unsigned* dst = gSorted + (size_t)b * BCAP;
        for (int i = lane; i < len; i += 64)
            if (gb + i < BCAP) dst[gb + i] = outL[off + i];
    }
}

// ---------- p4_build: quarter-bucket ELL (128 nodes, 32KB LDS -> 4/CU); also Tsc=Ts*isd ----------
__global__ __launch_bounds__(256) void p4_build(const unsigned* __restrict__ gSorted,
                                                const int* __restrict__ bucketCursor,
                                                int nb, int N, int* __restrict__ cnt,
                                                float* __restrict__ isd,
                                                int* __restrict__ ell,
                                                const float* __restrict__ Ts,
                                                float* __restrict__ Tsc) {
    __shared__ unsigned ellL[128 * CAPD];  // 32KB
    __shared__ int cntL[128];
    int bid = blockIdx.x, tid = threadIdx.x;
    int bucket = bid >> 2;
    unsigned sub = (unsigned)(bid & 3);
    int n0 = bid * 128;
    int nValid = min(128, N - n0);
    if (nValid <= 0) return;
    for (int i = tid; i < 128; i += 256) cntL[i] = 0;
    __syncthreads();
    int len = bucketCursor[bucket];
    if (len > BCAP) len = BCAP;
    const unsigned* seg = gSorted + (size_t)bucket * BCAP;
    for (int i = tid; i < len; i += 256) {
        unsigned e = seg[i];
        unsigned dl = e >> 23;
        if ((dl >> 7) == sub) {
            int r = (int)(dl & 127u);
            int p = atomicAdd(&cntL[r], 1);
            if (p < CAPD) ellL[r * CAPD + p] = e & 0x7FFFFFu;
        }
    }
    __syncthreads();
    int total = nValid * CAPD;
    const int* ellLi = (const int*)ellL;
    for (int i = tid; i < total; i += 256) {
        int row = i >> 6, pos = i & 63;
        int c = cntL[row];
        if (pos < min(c, CAPD))
            ell[(size_t)n0 * CAPD + i] = ellLi[i];
    }
    for (int i = tid; i < nValid; i += 256) {
        int c = cntL[i];
        float iv = rsqrtf(1.0f + (float)c);
        cnt[n0 + i] = c;
        isd[n0 + i] = iv;
        Tsc[n0 + i] = Ts[n0 + i] * iv;   // fused tsc (Ts complete: gemm1 finished)
    }
}

// ---------- layer-2 GEMM (isd scale in epilogue) ----------
__global__ __launch_bounds__(256) void gemm2_kernel(const uint* __restrict__ Hb,
                                                    const uint* __restrict__ Wt,
                                                    const float* __restrict__ isd,
                                                    uint* __restrict__ Tq,
                                                    float* __restrict__ Ts, int n) {
    __shared__ __align__(16) uint SH[16384];
    gemm_core(Hb, 1, Wt, isd, Tq, Ts, n, blockIdx.x * 128, threadIdx.x, SH);
}

// ---------- agg layer 1: single scale array Tsc = Ts*isd. Half-wave per node. ----------
__global__ __launch_bounds__(256) void agg_kernel(const uint* __restrict__ Tq,
                                                  const float* __restrict__ Tsc,
                                                  const int* __restrict__ ell,
                                                  const int* __restrict__ cnt,
                                                  const float* __restrict__ isd,
                                                  const float* __restrict__ bias,
                                                  uint* __restrict__ Hb, int n) {
    int node = (int)((blockIdx.x * 256 + threadIdx.x) >> 5);
    int ln = threadIdx.x & 31;
    if (node >= n) return;
    float di = isd[node];
    int c = cnt[node];
    if (c > CAPD) c = CAPD;
    const int* row = ell + (size_t)node * CAPD;
    float a0, a1, a2, a3, ssum;
    {
        uint v = Tq[(size_t)node * 32 + ln];
        float sc = Tsc[node];
        ssum = sc;
        a0 = sc * ub0(v); a1 = sc * ub1(v); a2 = sc * ub2(v); a3 = sc * ub3(v);
    }
    int j = 0;
    for (; j + 8 <= c; j += 8) {
        int4 sa = *reinterpret_cast<const int4*>(row + j);
        int4 sb = *reinterpret_cast<const int4*>(row + j + 4);
        uint v0 = Tq[(size_t)sa.x * 32 + ln]; float c0 = Tsc[sa.x];
        uint v1 = Tq[(size_t)sa.y * 32 + ln]; float c1 = Tsc[sa.y];
        uint v2 = Tq[(size_t)sa.z * 32 + ln]; float c2 = Tsc[sa.z];
        uint v3 = Tq[(size_t)sa.w * 32 + ln]; float c3 = Tsc[sa.w];
        uint v4 = Tq[(size_t)sb.x * 32 + ln]; float c4 = Tsc[sb.x];
        uint v5 = Tq[(size_t)sb.y * 32 + ln]; float c5 = Tsc[sb.y];
        uint v6 = Tq[(size_t)sb.z * 32 + ln]; float c6 = Tsc[sb.z];
        uint v7 = Tq[(size_t)sb.w * 32 + ln]; float c7 = Tsc[sb.w];
        ssum += ((c0 + c1) + (c2 + c3)) + ((c4 + c5) + (c6 + c7));
        a0 = fmaf(c0, ub0(v0), fmaf(c1, ub0(v1), fmaf(c2, ub0(v2), fmaf(c3, ub0(v3),
             fmaf(c4, ub0(v4), fmaf(c5, ub0(v5), fmaf(c6, ub0(v6), fmaf(c7, ub0(v7), a0))))))));
        a1 = fmaf(c0, ub1(v0), fmaf(c1, ub1(v1), fmaf(c2, ub1(v2), fmaf(c3, ub1(v3),
             fmaf(c4, ub1(v4), fmaf(c5, ub1(v5), fmaf(c6, ub1(v6), fmaf(c7, ub1(v7), a1))))))));
        a2 = fmaf(c0, ub2(v0), fmaf(c1, ub2(v1), fmaf(c2, ub2(v2), fmaf(c3, ub2(v3),
             fmaf(c4, ub2(v4), fmaf(c5, ub2(v5), fmaf(c6, ub2(v6), fmaf(c7, ub2(v7), a2))))))));
        a3 = fmaf(c0, ub3(v0), fmaf(c1, ub3(v1), fmaf(c2, ub3(v2), fmaf(c3, ub3(v3),
             fmaf(c4, ub3(v4), fmaf(c5, ub3(v5), fmaf(c6, ub3(v6), fmaf(c7, ub3(v7), a3))))))));
    }
    for (; j + 4 <= c; j += 4) {
        int4 s4 = *reinterpret_cast<const int4*>(row + j);
        uint v0 = Tq[(size_t)s4.x * 32 + ln]; float c0 = Tsc[s4.x];
        uint v1 = Tq[(size_t)s4.y * 32 + ln]; float c1 = Tsc[s4.y];
        uint v2 = Tq[(size_t)s4.z * 32 + ln]; float c2 = Tsc[s4.z];
        uint v3 = Tq[(size_t)s4.w * 32 + ln]; float c3 = Tsc[s4.w];
        ssum += (c0 + c1) + (c2 + c3);
        a0 = fmaf(c0, ub0(v0), fmaf(c1, ub0(v1), fmaf(c2, ub0(v2), fmaf(c3, ub0(v3), a0))));
        a1 = fmaf(c0, ub1(v0), fmaf(c1, ub1(v1), fmaf(c2, ub1(v2), fmaf(c3, ub1(v3), a1))));
        a2 = fmaf(c0, ub2(v0), fmaf(c1, ub2(v1), fmaf(c2, ub2(v2), fmaf(c3, ub2(v3), a2))));
        a3 = fmaf(c0, ub3(v0), fmaf(c1, ub3(v1), fmaf(c2, ub3(v2), fmaf(c3, ub3(v3), a3))));
    }
    for (; j < c; ++j) {
        int s = row[j];
        uint v = Tq[(size_t)s * 32 + ln];
        float sc = Tsc[s];
        ssum += sc;
        a0 = fmaf(sc, ub0(v), a0); a1 = fmaf(sc, ub1(v), a1);
        a2 = fmaf(sc, ub2(v), a2); a3 = fmaf(sc, ub3(v), a3);
    }
    float off = 128.f * ssum;
    float4 bv = *reinterpret_cast<const float4*>(bias + ln * 4);
    float h0 = fmaxf(fmaf(di, a0 - off, bv.x), 0.f);
    float h1 = fmaxf(fmaf(di, a1 - off, bv.y), 0.f);
    float h2 = fmaxf(fmaf(di, a2 - off, bv.z), 0.f);
    float h3 = fmaxf(fmaf(di, a3 - off, bv.w), 0.f);
    *reinterpret_cast<uint2*>(Hb + (size_t)node * 64 + ln * 2) =
        make_uint2(h_pack(h0, h1), h_pack(h2, h3));
}

// ---------- agg layer 2 + head: sc_j = Ts[j] (isd already in Tq scale) ----------
__global__ __launch_bounds__(256) void agg_out_kernel(const uint* __restrict__ Tq,
                                                      const float* __restrict__ Ts,
                                                      const int* __restrict__ ell,
                                                      const int* __restrict__ cnt,
                                                      const float* __restrict__ isd,
                                                      const float* __restrict__ bias,
                                                      const float* __restrict__ Wout,
                                                      const float* __restrict__ bout,
                                                      float* __restrict__ out, int n) {
    int node = (int)((blockIdx.x * 256 + threadIdx.x) >> 5);
    int ln = threadIdx.x & 31;
    if (node >= n) return;
    float di = isd[node];
    int c = cnt[node];
    if (c > CAPD) c = CAPD;
    const int* row = ell + (size_t)node * CAPD;
    float a0, a1, a2, a3, ssum;
    {
        uint v = Tq[(size_t)node * 32 + ln];
        float sc = Ts[node];
        ssum = sc;
        a0 = sc * ub0(v); a1 = sc * ub1(v); a2 = sc * ub2(v); a3 = sc * ub3(v);
    }
    int j = 0;
    for (; j + 8 <= c; j += 8) {
        int4 sa = *reinterpret_cast<const int4*>(row + j);
        int4 sb = *reinterpret_cast<const int4*>(row + j + 4);
        uint v0 = Tq[(size_t)sa.x * 32 + ln]; float c0 = Ts[sa.x];
        uint v1 = Tq[(size_t)sa.y * 32 + ln]; float c1 = Ts[sa.y];
        uint v2 = Tq[(size_t)sa.z * 32 + ln]; float c2 = Ts[sa.z];
        uint v3 = Tq[(size_t)sa.w * 32 + ln]; float c3 = Ts[sa.w];
        uint v4 = Tq[(size_t)sb.x * 32 + ln]; float c4 = Ts[sb.x];
        uint v5 = Tq[(size_t)sb.y * 32 + ln]; float c5 = Ts[sb.y];
        uint v6 = Tq[(size_t)sb.z * 32 + ln]; float c6 = Ts[sb.z];
        uint v7 = Tq[(size_t)sb.w * 32 + ln]; float c7 = Ts[sb.w];
        ssum += ((c0 + c1) + (c2 + c3)) + ((c4 + c5) + (c6 + c7));
        a0 = fmaf(c0, ub0(v0), fmaf(c1, ub0(v1), fmaf(c2, ub0(v2), fmaf(c3, ub0(v3),
             fmaf(c4, ub0(v4), fmaf(c5, ub0(v5), fmaf(c6, ub0(v6), fmaf(c7, ub0(v7), a0))))))));
        a1 = fmaf(c0, ub1(v0), fmaf(c1, ub1(v1), fmaf(c2, ub1(v2), fmaf(c3, ub1(v3),
             fmaf(c4, ub1(v4), fmaf(c5, ub1(v5), fmaf(c6, ub1(v6), fmaf(c7, ub1(v7), a1))))))));
        a2 = fmaf(c0, ub2(v0), fmaf(c1, ub2(v1), fmaf(c2, ub2(v2), fmaf(c3, ub2(v3),
             fmaf(c4, ub2(v4), fmaf(c5, ub2(v5), fmaf(c6, ub2(v6), fmaf(c7, ub2(v7), a2))))))));
        a3 = fmaf(c0, ub3(v0), fmaf(c1, ub3(v1), fmaf(c2, ub3(v2), fmaf(c3, ub3(v3),
             fmaf(c4, ub3(v4), fmaf(c5, ub3(v5), fmaf(c6, ub3(v6), fmaf(c7, ub3(v7), a3))))))));
    }
    for (; j + 4 <= c; j += 4) {
        int4 s4 = *reinterpret_cast<const int4*>(row + j);
        uint v0 = Tq[(size_t)s4.x * 32 + ln]; float c0 = Ts[s4.x];
        uint v1 = Tq[(size_t)s4.y * 32 + ln]; float c1 = Ts[s4.y];
        uint v2 = Tq[(size_t)s4.z * 32 + ln]; float c2 = Ts[s4.z];
        uint v3 = Tq[(size_t)s4.w * 32 + ln]; float c3 = Ts[s4.w];
        ssum += (c0 + c1) + (c2 + c3);
        a0 = fmaf(c0, ub0(v0), fmaf(c1, ub0(v1), fmaf(c2, ub0(v2), fmaf(c3, ub0(v3), a0))));
        a1 = fmaf(c0, ub1(v0), fmaf(c1, ub1(v1), fmaf(c2, ub1(v2), fmaf(c3, ub1(v3), a1))));
        a2 = fmaf(c0, ub2(v0), fmaf(c1, ub2(v1), fmaf(c2, ub2(v2), fmaf(c3, ub2(v3), a2))));
        a3 = fmaf(c0, ub3(v0), fmaf(c1, ub3(v1), fmaf(c2, ub3(v2), fmaf(c3, ub3(v3), a3))));
    }
    for (; j < c; ++j) {
        int s = row[j];
        uint v = Tq[(size_t)s * 32 + ln];
        float sc = Ts[s];
        ssum += sc;
        a0 = fmaf(sc, ub0(v), a0); a1 = fmaf(sc, ub1(v), a1);
        a2 = fmaf(sc, ub2(v), a2); a3 = fmaf(sc, ub3(v), a3);
    }
    float off = 128.f * ssum;
    float4 bv = *reinterpret_cast<const float4*>(bias + ln * 4);
    float4 wv = *reinterpret_cast<const float4*>(Wout + ln * 4);
    float h0 = fmaxf(fmaf(di, a0 - off, bv.x), 0.f);
    float h1 = fmaxf(fmaf(di, a1 - off, bv.y), 0.f);
    float h2 = fmaxf(fmaf(di, a2 - off, bv.z), 0.f);
    float h3 = fmaxf(fmaf(di, a3 - off, bv.w), 0.f);
    float v = fmaf(h0, wv.x, fmaf(h1, wv.y, fmaf(h2, wv.z, h3 * wv.w)));
#pragma unroll
    for (int off2 = 16; off2 > 0; off2 >>= 1) v += __shfl_xor(v, off2, 32);
    if (ln == 0) out[node] = 1.f / (1.f + expf(-(v + bout[0])));
}

extern "C" void kernel_launch(void* const* d_in, const int* in_sizes, int n_in,
                              void* d_out, int out_size, void* d_ws, size_t ws_size,
                              hipStream_t stream) {
    const float* x    = (const float*)d_in[0];
    const int*   ei   = (const int*)d_in[1];
    const float* W1   = (const float*)d_in[2];
    const float* b1   = (const float*)d_in[3];
    const float* W2   = (const float*)d_in[4];
    const float* b2   = (const float*)d_in[5];
    const float* Wout = (const float*)d_in[6];
    const float* bout = (const float*)d_in[7];
    float* out = (float*)d_out;

    const int N = in_sizes[0] / 128;
    const int E = in_sizes[1] / 2;
    const int* esrc = ei;
    const int* edst = ei + E;

    char* p = (char*)d_ws;
    auto alloc = [&](size_t bytes) {
        char* r = p;
        p += (bytes + 255) & ~(size_t)255;
        return (void*)r;
    };
    const int nb  = (N + BSZ - 1) / BSZ;       // p3 buckets (<=256)
    const int NB2 = (E + CHUNK - 1) / CHUNK;   // partition blocks

    int*   cnt = (int*)  alloc((size_t)N * 4);
    float* isd = (float*)alloc((size_t)N * 4);
    int*   ell = (int*)  alloc((size_t)N * CAPD * 4);
    uint*  Tq  = (uint*) alloc((size_t)N * 32 * 4);   // biased-u8 rows, 128 B/node
    float* Ts  = (float*)alloc((size_t)(N + 4) * 4);  // per-row scales
    float* Tsc = (float*)alloc((size_t)(N + 4) * 4);  // Ts*isd (layer-1 agg)
    uint*  Hb  = (uint*) alloc((size_t)N * 64 * 4);   // hidden, fp16 pairs
    uint*  Wt1 = (uint*) alloc(8192 * 4);
    uint*  Wt2 = (uint*) alloc(8192 * 4);
    unsigned* gSorted      = (unsigned*)alloc((size_t)nb * BCAP * 4);
    int*      bucketCursor = (int*)     alloc((size_t)nb * 4);

    const int gblocks = (N + 127) / 128;
    const int ablocks = (N + 7) / 8;   // one node per half-wave

    // prep: zero cursors + W transposes
    prep_kernel<<<3, 256, 0, stream>>>(bucketCursor, nb, W1, W2, Wt1, Wt2);
    // partition || layer-1 GEMM (heterogeneous grid, overlapped)
    p3gemm1<<<NB2 + gblocks, 256, 0, stream>>>(esrc, edst, E, nb, NB2, bucketCursor,
                                               gSorted, x, Wt1, Tq, Ts, N);
    // ELL build + cnt/isd + Tsc = Ts*isd
    p4_build<<<4 * nb, 256, 0, stream>>>(gSorted, bucketCursor, nb, N, cnt, isd, ell, Ts, Tsc);
    // Layer-1 agg
    agg_kernel<<<ablocks, 256, 0, stream>>>(Tq, Tsc, ell, cnt, isd, b1, Hb, N);
    // Layer-2 GEMM (isd scale in epilogue)
    gemm2_kernel<<<gblocks, 256, 0, stream>>>(Hb, Wt2, isd, Tq, Ts, N);
    // Layer-2 agg + head
    agg_out_kernel<<<ablocks, 256, 0, stream>>>(Tq, Ts, ell, cnt, isd, b2, Wout, bout, out, N);
}

// Round 19
// 156.292 us; speedup vs baseline: 1.2058x; 1.0642x over previous
//
#include <hip/hip_runtime.h>
#include <cstddef>

#define CAPD 64
#define BSZ 512        // nodes per bucket (p3 granularity)
#define BSH 9          // log2(BSZ)
#define CHUNK 8192     // edges per partition block
#define BCAP 12288     // per-bucket edge capacity (mean 8163, sigma ~90 -> safe)

typedef unsigned int uint;
typedef unsigned short ushort;
typedef unsigned char uchar;
typedef float f32x4 __attribute__((ext_vector_type(4)));
typedef _Float16 f16x8 __attribute__((ext_vector_type(8)));  // 8 fp16 = 4 VGPRs

// fp16 helpers: word = dimEven | dimOdd<<16
__device__ inline float h_lo(uint v) {
    union { ushort u; _Float16 h; } c; c.u = (ushort)(v & 0xFFFFu); return (float)c.h;
}
__device__ inline float h_hi(uint v) {
    union { ushort u; _Float16 h; } c; c.u = (ushort)(v >> 16); return (float)c.h;
}
__device__ inline ushort h_bits(float x) {
    union { _Float16 h; ushort u; } c; c.h = (_Float16)x; return c.u;
}
__device__ inline uint h_pack(float a, float b) {
    return (uint)h_bits(a) | ((uint)h_bits(b) << 16);
}
// biased-uint8 byte k -> float (maps to v_cvt_f32_ubyte[k])
__device__ inline float ub0(uint v) { return (float)(v & 0xFFu); }
__device__ inline float ub1(uint v) { return (float)((v >> 8) & 0xFFu); }
__device__ inline float ub2(uint v) { return (float)((v >> 16) & 0xFFu); }
__device__ inline float ub3(uint v) { return (float)(v >> 24); }

// ---------- prep: block 0 zeros bucketCursor; blocks 1,2 transpose W1,W2 ----------
__global__ __launch_bounds__(256) void prep_kernel(int* __restrict__ bucketCursor, int nb,
                                                   const float* __restrict__ W1,
                                                   const float* __restrict__ W2,
                                                   uint* __restrict__ Wt1,
                                                   uint* __restrict__ Wt2) {
    __shared__ float ws[128][129];
    int bid = blockIdx.x, tid = threadIdx.x;
    if (bid == 0) {
        for (int i = tid; i < nb; i += 256) bucketCursor[i] = 0;
        return;
    }
    const float* W = (bid == 2) ? W2 : W1;
    uint* O = (bid == 2) ? Wt2 : Wt1;
#pragma unroll
    for (int j = 0; j < 16; ++j) {
        int q = tid + 256 * j;
        int k = q >> 5, c = (q & 31) * 4;
        float4 v = *reinterpret_cast<const float4*>(W + k * 128 + c);
        ws[k][c] = v.x; ws[k][c + 1] = v.y; ws[k][c + 2] = v.z; ws[k][c + 3] = v.w;
    }
    __syncthreads();
#pragma unroll
    for (int j = 0; j < 32; ++j) {
        int q = tid + 256 * j;
        int ncol = q >> 6, kw = q & 63;
        O[q] = h_pack(ws[2 * kw][ncol], ws[2 * kw + 1][ncol]);
    }
}

// ---------- shared GEMM core: fp16 MFMA, biased-uint8 quantized output ----------
// Tq[node][128] biased-u8 (32 words); Ts[node] = rowmax/127 (after optional `scale`).
__device__ __forceinline__ void gemm_core(const void* __restrict__ A, int aF16,
                                          const uint* __restrict__ Wt,
                                          const float* __restrict__ scale,   // nullptr -> 1
                                          uint* __restrict__ Tq,
                                          float* __restrict__ Ts,
                                          int n, int m0, int tid, uint* SH) {
    char* shb = (char*)SH;
    if (aF16) {
        const uint* Af = (const uint*)A;
#pragma unroll
        for (int j = 0; j < 8; ++j) {
            int q = tid + 256 * j;
            int row = q >> 4, c16 = q & 15;
            int grow = m0 + row;
            uint4 v = make_uint4(0u, 0u, 0u, 0u);
            if (grow < n) v = *reinterpret_cast<const uint4*>(Af + (size_t)grow * 64 + c16 * 4);
            *reinterpret_cast<uint4*>(shb + row * 256 + ((c16 * 16) ^ ((row & 7) << 4))) = v;
        }
    } else {
        const float* Af = (const float*)A;
#pragma unroll
        for (int j = 0; j < 8; ++j) {
            int q = tid + 256 * j;
            int row = q >> 4, c16 = q & 15;
            int grow = m0 + row;
            uint4 o = make_uint4(0u, 0u, 0u, 0u);
            if (grow < n) {
                float4 v0 = *reinterpret_cast<const float4*>(Af + (size_t)grow * 128 + c16 * 8);
                float4 v1 = *reinterpret_cast<const float4*>(Af + (size_t)grow * 128 + c16 * 8 + 4);
                o.x = h_pack(v0.x, v0.y); o.y = h_pack(v0.z, v0.w);
                o.z = h_pack(v1.x, v1.y); o.w = h_pack(v1.z, v1.w);
            }
            *reinterpret_cast<uint4*>(shb + row * 256 + ((c16 * 16) ^ ((row & 7) << 4))) = o;
        }
    }
#pragma unroll
    for (int j = 0; j < 8; ++j) {
        int q = tid + 256 * j;
        int col = q >> 4, c16 = q & 15;
        uint4 v = *reinterpret_cast<const uint4*>(Wt + col * 64 + c16 * 4);
        *reinterpret_cast<uint4*>(shb + 32768 + col * 256 + ((c16 * 16) ^ ((col & 7) << 4))) = v;
    }
    __syncthreads();

    const int w = tid >> 6, l = tid & 63;
    const int lrow = l & 15, kg = l >> 4;
    const int swz = (lrow & 7) << 4;

    f32x4 acc[2][8] = {};
#pragma unroll
    for (int kk = 0; kk < 4; ++kk) {
        const int koff = (kk * 64 + kg * 16) ^ swz;
        f16x8 a[2], b[8];
#pragma unroll
        for (int mr = 0; mr < 2; ++mr) {
            int r = w * 32 + mr * 16 + lrow;
            a[mr] = *reinterpret_cast<const f16x8*>(shb + r * 256 + koff);
        }
#pragma unroll
        for (int nc = 0; nc < 8; ++nc) {
            int c = nc * 16 + lrow;
            b[nc] = *reinterpret_cast<const f16x8*>(shb + 32768 + c * 256 + koff);
        }
#pragma unroll
        for (int mr = 0; mr < 2; ++mr)
#pragma unroll
            for (int nc = 0; nc < 8; ++nc)
                acc[mr][nc] = __builtin_amdgcn_mfma_f32_16x16x32_f16(a[mr], b[nc], acc[mr][nc], 0, 0, 0);
    }
    __syncthreads();

    // C/D layout (m89): col = lane&15, row = (lane>>4)*4 + reg.
    ushort* Cs = (ushort*)SH;   // [128][136]
#pragma unroll
    for (int mr = 0; mr < 2; ++mr) {
        int rb = w * 32 + mr * 16 + kg * 4;
#pragma unroll
        for (int i = 0; i < 4; ++i) {
            int grow = m0 + rb + i;
            float s = scale ? ((grow < n) ? scale[grow] : 0.f) : 1.f;
#pragma unroll
            for (int nc = 0; nc < 8; ++nc)
                Cs[(rb + i) * 136 + nc * 16 + lrow] = h_bits(s * acc[mr][nc][i]);
        }
    }
    __syncthreads();
    const uint* Cw = (const uint*)SH;             // stride 68 words/row
#pragma unroll
    for (int j = 0; j < 8; ++j) {
        int q = tid + 256 * j;
        int row = q >> 4, c8 = q & 15;
        int grow = m0 + row;
        uint4 v = *reinterpret_cast<const uint4*>(Cw + row * 68 + c8 * 4);
        float f0 = h_lo(v.x), f1 = h_hi(v.x), f2 = h_lo(v.y), f3 = h_hi(v.y);
        float f4 = h_lo(v.z), f5 = h_hi(v.z), f6 = h_lo(v.w), f7 = h_hi(v.w);
        float mx = fmaxf(fmaxf(fmaxf(fabsf(f0), fabsf(f1)), fmaxf(fabsf(f2), fabsf(f3))),
                         fmaxf(fmaxf(fabsf(f4), fabsf(f5)), fmaxf(fabsf(f6), fabsf(f7))));
#pragma unroll
        for (int off = 8; off > 0; off >>= 1) mx = fmaxf(mx, __shfl_xor(mx, off, 16));
        mx = fmaxf(mx, 1e-20f);
        float inv = 127.f / mx;
        int q0 = (int)rintf(f0 * inv) + 128, q1 = (int)rintf(f1 * inv) + 128;
        int q2 = (int)rintf(f2 * inv) + 128, q3 = (int)rintf(f3 * inv) + 128;
        int q4 = (int)rintf(f4 * inv) + 128, q5 = (int)rintf(f5 * inv) + 128;
        int q6 = (int)rintf(f6 * inv) + 128, q7 = (int)rintf(f7 * inv) + 128;
        uint w0 = (uint)q0 | ((uint)q1 << 8) | ((uint)q2 << 16) | ((uint)q3 << 24);
        uint w1 = (uint)q4 | ((uint)q5 << 8) | ((uint)q6 << 16) | ((uint)q7 << 24);
        if (grow < n) {
            *reinterpret_cast<uint2*>(Tq + (size_t)grow * 32 + c8 * 2) = make_uint2(w0, w1);
            if (c8 == 0) Ts[grow] = mx * (1.f / 127.f);
        }
    }
}

// ---------- p3gemm1: blocks [0,NB2) partition; rest run layer-1 GEMM (overlapped) ----------
__global__ __launch_bounds__(256) void p3gemm1(const int* __restrict__ esrc,
                                               const int* __restrict__ edst, int E,
                                               int nb, int NB2,
                                               int* __restrict__ bucketCursor,
                                               unsigned* __restrict__ gSorted,
                                               const float* __restrict__ x,
                                               const uint* __restrict__ Wt1,
                                               uint* __restrict__ Tq,
                                               float* __restrict__ Ts, int N) {
    __shared__ __align__(16) char SHB[78848];  // 77KB (union of both paths)
    int bid = blockIdx.x, tid = threadIdx.x;
    if (bid >= NB2) {
        gemm_core(x, 0, Wt1, nullptr, Tq, Ts, N, (bid - NB2) * 128, tid, (uint*)SHB);
        return;
    }
    uint*  payL = (uint*)SHB;                 // 32KB
    uint*  outL = (uint*)(SHB + 32768);       // 32KB
    uchar* bktL = (uchar*)(SHB + 65536);      // 8KB
    int*   hist   = (int*)(SHB + 73728);
    int*   segoff = hist + 256;
    int*   cursor = segoff + 256;
    int*   gbase  = cursor + 256;
    int*   sc     = gbase + 256;
    int e0 = bid * CHUNK;
    int m = min(E - e0, CHUNK);
    for (int i = tid; i < m; i += 256) {
        unsigned d = (unsigned)edst[e0 + i];
        unsigned s = (unsigned)esrc[e0 + i];
        payL[i] = s | ((d & (BSZ - 1)) << 23);
        bktL[i] = (uchar)(d >> BSH);
    }
    hist[tid] = 0;
    __syncthreads();
    for (int i = tid; i < m; i += 256)
        atomicAdd(&hist[bktL[i]], 1);
    __syncthreads();
    sc[tid] = hist[tid];
    __syncthreads();
    for (int off = 1; off < 256; off <<= 1) {
        int v = (tid >= off) ? sc[tid - off] : 0;
        __syncthreads();
        sc[tid] += v;
        __syncthreads();
    }
    segoff[tid] = sc[tid] - hist[tid];
    cursor[tid] = segoff[tid];
    if (tid < nb && hist[tid] > 0) gbase[tid] = atomicAdd(&bucketCursor[tid], hist[tid]);
    __syncthreads();
    for (int i = tid; i < m; i += 256) {
        int b = (int)bktL[i];
        int p = atomicAdd(&cursor[b], 1);
        outL[p] = payL[i];
    }
    __syncthreads();
    int wave = tid >> 6, lane = tid & 63;
    for (int b = wave; b < nb; b += 4) {
        int off = segoff[b], len = hist[b];
        if (len == 0) continue;
        int gb = gbase[b];
        unsigned* dst = gSorted + (size_t)b * BCAP;
        for (int i = lane; i < len; i += 64)
            if (gb + i < BCAP) dst[gb + i] = outL[off + i];
    }
}

// ---------- p4_build: quarter-bucket ELL (128 nodes, 32KB LDS -> 4/CU); also Tsc=Ts*isd ----------
__global__ __launch_bounds__(256) void p4_build(const unsigned* __restrict__ gSorted,
                                                const int* __restrict__ bucketCursor,
                                                int nb, int N, int* __restrict__ cnt,
                                                float* __restrict__ isd,
                                                int* __restrict__ ell,
                                                const float* __restrict__ Ts,
                                                float* __restrict__ Tsc) {
    __shared__ unsigned ellL[128 * CAPD];  // 32KB
    __shared__ int cntL[128];
    int bid = blockIdx.x, tid = threadIdx.x;
    int bucket = bid >> 2;
    unsigned sub = (unsigned)(bid & 3);
    int n0 = bid * 128;
    int nValid = min(128, N - n0);
    if (nValid <= 0) return;
    for (int i = tid; i < 128; i += 256) cntL[i] = 0;
    __syncthreads();
    int len = bucketCursor[bucket];
    if (len > BCAP) len = BCAP;
    const unsigned* seg = gSorted + (size_t)bucket * BCAP;
    for (int i = tid; i < len; i += 256) {
        unsigned e = seg[i];
        unsigned dl = e >> 23;
        if ((dl >> 7) == sub) {
            int r = (int)(dl & 127u);
            int p = atomicAdd(&cntL[r], 1);
            if (p < CAPD) ellL[r * CAPD + p] = e & 0x7FFFFFu;
        }
    }
    __syncthreads();
    int total = nValid * CAPD;
    const int* ellLi = (const int*)ellL;
    for (int i = tid; i < total; i += 256) {
        int row = i >> 6, pos = i & 63;
        int c = cntL[row];
        if (pos < min(c, CAPD))
            ell[(size_t)n0 * CAPD + i] = ellLi[i];
    }
    for (int i = tid; i < nValid; i += 256) {
        int c = cntL[i];
        float iv = rsqrtf(1.0f + (float)c);
        cnt[n0 + i] = c;
        isd[n0 + i] = iv;
        Tsc[n0 + i] = Ts[n0 + i] * iv;   // fused tsc (Ts complete: gemm1 finished)
    }
}

// ---------- layer-2 GEMM (isd scale in epilogue) ----------
__global__ __launch_bounds__(256) void gemm2_kernel(const uint* __restrict__ Hb,
                                                    const uint* __restrict__ Wt,
                                                    const float* __restrict__ isd,
                                                    uint* __restrict__ Tq,
                                                    float* __restrict__ Ts, int n) {
    __shared__ __align__(16) uint SH[16384];
    gemm_core(Hb, 1, Wt, isd, Tq, Ts, n, blockIdx.x * 128, threadIdx.x, SH);
}

// ---------- agg layer 1: one node per QUARTER-wave (16 lanes x uint2 = 8 dims/lane) ----------
// a_dim = sum Tsc_j*u - 128*sum Tsc_j ; H = fp16(relu(isd_i*a + bias))
__global__ __launch_bounds__(256) void agg_kernel(const uint* __restrict__ Tq,
                                                  const float* __restrict__ Tsc,
                                                  const int* __restrict__ ell,
                                                  const int* __restrict__ cnt,
                                                  const float* __restrict__ isd,
                                                  const float* __restrict__ bias,
                                                  uint* __restrict__ Hb, int n) {
    int node = (int)((blockIdx.x * 256 + threadIdx.x) >> 4);
    int ln = threadIdx.x & 15;   // dims 8ln..8ln+7
    if (node >= n) return;
    const uint2* T2 = (const uint2*)Tq;   // 16 uint2 per row
    float di = isd[node];
    int c = cnt[node];
    if (c > CAPD) c = CAPD;
    const int* row = ell + (size_t)node * CAPD;
    float a0, a1, a2, a3, a4, a5, a6, a7, ssum;
    {
        uint2 v = T2[(size_t)node * 16 + ln];
        float sc = Tsc[node];
        ssum = sc;
        a0 = sc * ub0(v.x); a1 = sc * ub1(v.x); a2 = sc * ub2(v.x); a3 = sc * ub3(v.x);
        a4 = sc * ub0(v.y); a5 = sc * ub1(v.y); a6 = sc * ub2(v.y); a7 = sc * ub3(v.y);
    }
    int j = 0;
    for (; j + 8 <= c; j += 8) {
        int4 sa = *reinterpret_cast<const int4*>(row + j);
        int4 sb = *reinterpret_cast<const int4*>(row + j + 4);
        uint2 v0 = T2[(size_t)sa.x * 16 + ln]; float c0 = Tsc[sa.x];
        uint2 v1 = T2[(size_t)sa.y * 16 + ln]; float c1 = Tsc[sa.y];
        uint2 v2 = T2[(size_t)sa.z * 16 + ln]; float c2 = Tsc[sa.z];
        uint2 v3 = T2[(size_t)sa.w * 16 + ln]; float c3 = Tsc[sa.w];
        uint2 v4 = T2[(size_t)sb.x * 16 + ln]; float c4 = Tsc[sb.x];
        uint2 v5 = T2[(size_t)sb.y * 16 + ln]; float c5 = Tsc[sb.y];
        uint2 v6 = T2[(size_t)sb.z * 16 + ln]; float c6 = Tsc[sb.z];
        uint2 v7 = T2[(size_t)sb.w * 16 + ln]; float c7 = Tsc[sb.w];
        ssum += ((c0 + c1) + (c2 + c3)) + ((c4 + c5) + (c6 + c7));
        a0 = fmaf(c0, ub0(v0.x), fmaf(c1, ub0(v1.x), fmaf(c2, ub0(v2.x), fmaf(c3, ub0(v3.x),
             fmaf(c4, ub0(v4.x), fmaf(c5, ub0(v5.x), fmaf(c6, ub0(v6.x), fmaf(c7, ub0(v7.x), a0))))))));
        a1 = fmaf(c0, ub1(v0.x), fmaf(c1, ub1(v1.x), fmaf(c2, ub1(v2.x), fmaf(c3, ub1(v3.x),
             fmaf(c4, ub1(v4.x), fmaf(c5, ub1(v5.x), fmaf(c6, ub1(v6.x), fmaf(c7, ub1(v7.x), a1))))))));
        a2 = fmaf(c0, ub2(v0.x), fmaf(c1, ub2(v1.x), fmaf(c2, ub2(v2.x), fmaf(c3, ub2(v3.x),
             fmaf(c4, ub2(v4.x), fmaf(c5, ub2(v5.x), fmaf(c6, ub2(v6.x), fmaf(c7, ub2(v7.x), a2))))))));
        a3 = fmaf(c0, ub3(v0.x), fmaf(c1, ub3(v1.x), fmaf(c2, ub3(v2.x), fmaf(c3, ub3(v3.x),
             fmaf(c4, ub3(v4.x), fmaf(c5, ub3(v5.x), fmaf(c6, ub3(v6.x), fmaf(c7, ub3(v7.x), a3))))))));
        a4 = fmaf(c0, ub0(v0.y), fmaf(c1, ub0(v1.y), fmaf(c2, ub0(v2.y), fmaf(c3, ub0(v3.y),
             fmaf(c4, ub0(v4.y), fmaf(c5, ub0(v5.y), fmaf(c6, ub0(v6.y), fmaf(c7, ub0(v7.y), a4))))))));
        a5 = fmaf(c0, ub1(v0.y), fmaf(c1, ub1(v1.y), fmaf(c2, ub1(v2.y), fmaf(c3, ub1(v3.y),
             fmaf(c4, ub1(v4.y), fmaf(c5, ub1(v5.y), fmaf(c6, ub1(v6.y), fmaf(c7, ub1(v7.y), a5))))))));
        a6 = fmaf(c0, ub2(v0.y), fmaf(c1, ub2(v1.y), fmaf(c2, ub2(v2.y), fmaf(c3, ub2(v3.y),
             fmaf(c4, ub2(v4.y), fmaf(c5, ub2(v5.y), fmaf(c6, ub2(v6.y), fmaf(c7, ub2(v7.y), a6))))))));
        a7 = fmaf(c0, ub3(v0.y), fmaf(c1, ub3(v1.y), fmaf(c2, ub3(v2.y), fmaf(c3, ub3(v3.y),
             fmaf(c4, ub3(v4.y), fmaf(c5, ub3(v5.y), fmaf(c6, ub3(v6.y), fmaf(c7, ub3(v7.y), a7))))))));
    }
    for (; j + 4 <= c; j += 4) {
        int4 s4 = *reinterpret_cast<const int4*>(row + j);
        uint2 v0 = T2[(size_t)s4.x * 16 + ln]; float c0 = Tsc[s4.x];
        uint2 v1 = T2[(size_t)s4.y * 16 + ln]; float c1 = Tsc[s4.y];
        uint2 v2 = T2[(size_t)s4.z * 16 + ln]; float c2 = Tsc[s4.z];
        uint2 v3 = T2[(size_t)s4.w * 16 + ln]; float c3 = Tsc[s4.w];
        ssum += (c0 + c1) + (c2 + c3);
        a0 = fmaf(c0, ub0(v0.x), fmaf(c1, ub0(v1.x), fmaf(c2, ub0(v2.x), fmaf(c3, ub0(v3.x), a0))));
        a1 = fmaf(c0, ub1(v0.x), fmaf(c1, ub1(v1.x), fmaf(c2, ub1(v2.x), fmaf(c3, ub1(v3.x), a1))));
        a2 = fmaf(c0, ub2(v0.x), fmaf(c1, ub2(v1.x), fmaf(c2, ub2(v2.x), fmaf(c3, ub2(v3.x), a2))));
        a3 = fmaf(c0, ub3(v0.x), fmaf(c1, ub3(v1.x), fmaf(c2, ub3(v2.x), fmaf(c3, ub3(v3.x), a3))));
        a4 = fmaf(c0, ub0(v0.y), fmaf(c1, ub0(v1.y), fmaf(c2, ub0(v2.y), fmaf(c3, ub0(v3.y), a4))));
        a5 = fmaf(c0, ub1(v0.y), fmaf(c1, ub1(v1.y), fmaf(c2, ub1(v2.y), fmaf(c3, ub1(v3.y), a5))));
        a6 = fmaf(c0, ub2(v0.y), fmaf(c1, ub2(v1.y), fmaf(c2, ub2(v2.y), fmaf(c3, ub2(v3.y), a6))));
        a7 = fmaf(c0, ub3(v0.y), fmaf(c1, ub3(v1.y), fmaf(c2, ub3(v2.y), fmaf(c3, ub3(v3.y), a7))));
    }
    for (; j < c; ++j) {
        int s = row[j];
        uint2 v = T2[(size_t)s * 16 + ln];
        float sc = Tsc[s];
        ssum += sc;
        a0 = fmaf(sc, ub0(v.x), a0); a1 = fmaf(sc, ub1(v.x), a1);
        a2 = fmaf(sc, ub2(v.x), a2); a3 = fmaf(sc, ub3(v.x), a3);
        a4 = fmaf(sc, ub0(v.y), a4); a5 = fmaf(sc, ub1(v.y), a5);
        a6 = fmaf(sc, ub2(v.y), a6); a7 = fmaf(sc, ub3(v.y), a7);
    }
    float off = 128.f * ssum;
    float4 bv0 = *reinterpret_cast<const float4*>(bias + ln * 8);
    float4 bv1 = *reinterpret_cast<const float4*>(bias + ln * 8 + 4);
    float h0 = fmaxf(fmaf(di, a0 - off, bv0.x), 0.f);
    float h1 = fmaxf(fmaf(di, a1 - off, bv0.y), 0.f);
    float h2 = fmaxf(fmaf(di, a2 - off, bv0.z), 0.f);
    float h3 = fmaxf(fmaf(di, a3 - off, bv0.w), 0.f);
    float h4 = fmaxf(fmaf(di, a4 - off, bv1.x), 0.f);
    float h5 = fmaxf(fmaf(di, a5 - off, bv1.y), 0.f);
    float h6 = fmaxf(fmaf(di, a6 - off, bv1.z), 0.f);
    float h7 = fmaxf(fmaf(di, a7 - off, bv1.w), 0.f);
    uint4 o;
    o.x = h_pack(h0, h1); o.y = h_pack(h2, h3);
    o.z = h_pack(h4, h5); o.w = h_pack(h6, h7);
    *reinterpret_cast<uint4*>(Hb + (size_t)node * 64 + ln * 4) = o;
}

// ---------- agg layer 2 + head: quarter-wave per node; sc_j = Ts[j] ----------
__global__ __launch_bounds__(256) void agg_out_kernel(const uint* __restrict__ Tq,
                                                      const float* __restrict__ Ts,
                                                      const int* __restrict__ ell,
                                                      const int* __restrict__ cnt,
                                                      const float* __restrict__ isd,
                                                      const float* __restrict__ bias,
                                                      const float* __restrict__ Wout,
                                                      const float* __restrict__ bout,
                                                      float* __restrict__ out, int n) {
    int node = (int)((blockIdx.x * 256 + threadIdx.x) >> 4);
    int ln = threadIdx.x & 15;   // dims 8ln..8ln+7
    if (node >= n) return;
    const uint2* T2 = (const uint2*)Tq;
    float di = isd[node];
    int c = cnt[node];
    if (c > CAPD) c = CAPD;
    const int* row = ell + (size_t)node * CAPD;
    float a0, a1, a2, a3, a4, a5, a6, a7, ssum;
    {
        uint2 v = T2[(size_t)node * 16 + ln];
        float sc = Ts[node];
        ssum = sc;
        a0 = sc * ub0(v.x); a1 = sc * ub1(v.x); a2 = sc * ub2(v.x); a3 = sc * ub3(v.x);
        a4 = sc * ub0(v.y); a5 = sc * ub1(v.y); a6 = sc * ub2(v.y); a7 = sc * ub3(v.y);
    }
    int j = 0;
    for (; j + 8 <= c; j += 8) {
        int4 sa = *reinterpret_cast<const int4*>(row + j);
        int4 sb = *reinterpret_cast<const int4*>(row + j + 4);
        uint2 v0 = T2[(size_t)sa.x * 16 + ln]; float c0 = Ts[sa.x];
        uint2 v1 = T2[(size_t)sa.y * 16 + ln]; float c1 = Ts[sa.y];
        uint2 v2 = T2[(size_t)sa.z * 16 + ln]; float c2 = Ts[sa.z];
        uint2 v3 = T2[(size_t)sa.w * 16 + ln]; float c3 = Ts[sa.w];
        uint2 v4 = T2[(size_t)sb.x * 16 + ln]; float c4 = Ts[sb.x];
        uint2 v5 = T2[(size_t)sb.y * 16 + ln]; float c5 = Ts[sb.y];
        uint2 v6 = T2[(size_t)sb.z * 16 + ln]; float c6 = Ts[sb.z];
        uint2 v7 = T2[(size_t)sb.w * 16 + ln]; float c7 = Ts[sb.w];
        ssum += ((c0 + c1) + (c2 + c3)) + ((c4 + c5) + (c6 + c7));
        a0 = fmaf(c0, ub0(v0.x), fmaf(c1, ub0(v1.x), fmaf(c2, ub0(v2.x), fmaf(c3, ub0(v3.x),
             fmaf(c4, ub0(v4.x), fmaf(c5, ub0(v5.x), fmaf(c6, ub0(v6.x), fmaf(c7, ub0(v7.x), a0))))))));
        a1 = fmaf(c0, ub1(v0.x), fmaf(c1, ub1(v1.x), fmaf(c2, ub1(v2.x), fmaf(c3, ub1(v3.x),
             fmaf(c4, ub1(v4.x), fmaf(c5, ub1(v5.x), fmaf(c6, ub1(v6.x), fmaf(c7, ub1(v7.x), a1))))))));
        a2 = fmaf(c0, ub2(v0.x), fmaf(c1, ub2(v1.x), fmaf(c2, ub2(v2.x), fmaf(c3, ub2(v3.x),
             fmaf(c4, ub2(v4.x), fmaf(c5, ub2(v5.x), fmaf(c6, ub2(v6.x), fmaf(c7, ub2(v7.x), a2))))))));
        a3 = fmaf(c0, ub3(v0.x), fmaf(c1, ub3(v1.x), fmaf(c2, ub3(v2.x), fmaf(c3, ub3(v3.x),
             fmaf(c4, ub3(v4.x), fmaf(c5, ub3(v5.x), fmaf(c6, ub3(v6.x), fmaf(c7, ub3(v7.x), a3))))))));
        a4 = fmaf(c0, ub0(v0.y), fmaf(c1, ub0(v1.y), fmaf(c2, ub0(v2.y), fmaf(c3, ub0(v3.y),
             fmaf(c4, ub0(v4.y), fmaf(c5, ub0(v5.y), fmaf(c6, ub0(v6.y), fmaf(c7, ub0(v7.y), a4))))))));
        a5 = fmaf(c0, ub1(v0.y), fmaf(c1, ub1(v1.y), fmaf(c2, ub1(v2.y), fmaf(c3, ub1(v3.y),
             fmaf(c4, ub1(v4.y), fmaf(c5, ub1(v5.y), fmaf(c6, ub1(v6.y), fmaf(c7, ub1(v7.y), a5))))))));
        a6 = fmaf(c0, ub2(v0.y), fmaf(c1, ub2(v1.y), fmaf(c2, ub2(v2.y), fmaf(c3, ub2(v3.y),
             fmaf(c4, ub2(v4.y), fmaf(c5, ub2(v5.y), fmaf(c6, ub2(v6.y), fmaf(c7, ub2(v7.y), a6))))))));
        a7 = fmaf(c0, ub3(v0.y), fmaf(c1, ub3(v1.y), fmaf(c2, ub3(v2.y), fmaf(c3, ub3(v3.y),
             fmaf(c4, ub3(v4.y), fmaf(c5, ub3(v5.y), fmaf(c6, ub3(v6.y), fmaf(c7, ub3(v7.y), a7))))))));
    }
    for (; j + 4 <= c; j += 4) {
        int4 s4 = *reinterpret_cast<const int4*>(row + j);
        uint2 v0 = T2[(size_t)s4.x * 16 + ln]; float c0 = Ts[s4.x];
        uint2 v1 = T2[(size_t)s4.y * 16 + ln]; float c1 = Ts[s4.y];
        uint2 v2 = T2[(size_t)s4.z * 16 + ln]; float c2 = Ts[s4.z];
        uint2 v3 = T2[(size_t)s4.w * 16 + ln]; float c3 = Ts[s4.w];
        ssum += (c0 + c1) + (c2 + c3);
        a0 = fmaf(c0, ub0(v0.x), fmaf(c1, ub0(v1.x), fmaf(c2, ub0(v2.x), fmaf(c3, ub0(v3.x), a0))));
        a1 = fmaf(c0, ub1(v0.x), fmaf(c1, ub1(v1.x), fmaf(c2, ub1(v2.x), fmaf(c3, ub1(v3.x), a1))));
        a2 = fmaf(c0, ub2(v0.x), fmaf(c1, ub2(v1.x), fmaf(c2, ub2(v2.x), fmaf(c3, ub2(v3.x), a2))));
        a3 = fmaf(c0, ub3(v0.x), fmaf(c1, ub3(v1.x), fmaf(c2, ub3(v2.x), fmaf(c3, ub3(v3.x), a3))));
        a4 = fmaf(c0, ub0(v0.y), fmaf(c1, ub0(v1.y), fmaf(c2, ub0(v2.y), fmaf(c3, ub0(v3.y), a4))));
        a5 = fmaf(c0, ub1(v0.y), fmaf(c1, ub1(v1.y), fmaf(c2, ub1(v2.y), fmaf(c3, ub1(v3.y), a5))));
        a6 = fmaf(c0, ub2(v0.y), fmaf(c1, ub2(v1.y), fmaf(c2, ub2(v2.y), fmaf(c3, ub2(v3.y), a6))));
        a7 = fmaf(c0, ub3(v0.y), fmaf(c1, ub3(v1.y), fmaf(c2, ub3(v2.y), fmaf(c3, ub3(v3.y), a7))));
    }
    for (; j < c; ++j) {
        int s = row[j];
        uint2 v = T2[(size_t)s * 16 + ln];
        float sc = Ts[s];
        ssum += sc;
        a0 = fmaf(sc, ub0(v.x), a0); a1 = fmaf(sc, ub1(v.x), a1);
        a2 = fmaf(sc, ub2(v.x), a2); a3 = fmaf(sc, ub3(v.x), a3);
        a4 = fmaf(sc, ub0(v.y), a4); a5 = fmaf(sc, ub1(v.y), a5);
        a6 = fmaf(sc, ub2(v.y), a6); a7 = fmaf(sc, ub3(v.y), a7);
    }
    float off = 128.f * ssum;
    float4 bv0 = *reinterpret_cast<const float4*>(bias + ln * 8);
    float4 bv1 = *reinterpret_cast<const float4*>(bias + ln * 8 + 4);
    float4 wv0 = *reinterpret_cast<const float4*>(Wout + ln * 8);
    float4 wv1 = *reinterpret_cast<const float4*>(Wout + ln * 8 + 4);
    float h0 = fmaxf(fmaf(di, a0 - off, bv0.x), 0.f);
    float h1 = fmaxf(fmaf(di, a1 - off, bv0.y), 0.f);
    float h2 = fmaxf(fmaf(di, a2 - off, bv0.z), 0.f);
    float h3 = fmaxf(fmaf(di, a3 - off, bv0.w), 0.f);
    float h4 = fmaxf(fmaf(di, a4 - off, bv1.x), 0.f);
    float h5 = fmaxf(fmaf(di, a5 - off, bv1.y), 0.f);
    float h6 = fmaxf(fmaf(di, a6 - off, bv1.z), 0.f);
    float h7 = fmaxf(fmaf(di, a7 - off, bv1.w), 0.f);
    float v = fmaf(h0, wv0.x, fmaf(h1, wv0.y, fmaf(h2, wv0.z, fmaf(h3, wv0.w,
              fmaf(h4, wv1.x, fmaf(h5, wv1.y, fmaf(h6, wv1.z, h7 * wv1.w)))))));
#pragma unroll
    for (int off2 = 8; off2 > 0; off2 >>= 1) v += __shfl_xor(v, off2, 16);
    if (ln == 0) out[node] = 1.f / (1.f + expf(-(v + bout[0])));
}

extern "C" void kernel_launch(void* const* d_in, const int* in_sizes, int n_in,
                              void* d_out, int out_size, void* d_ws, size_t ws_size,
                              hipStream_t stream) {
    const float* x    = (const float*)d_in[0];
    const int*   ei   = (const int*)d_in[1];
    const float* W1   = (const float*)d_in[2];
    const float* b1   = (const float*)d_in[3];
    const float* W2   = (const float*)d_in[4];
    const float* b2   = (const float*)d_in[5];
    const float* Wout = (const float*)d_in[6];
    const float* bout = (const float*)d_in[7];
    float* out = (float*)d_out;

    const int N = in_sizes[0] / 128;
    const int E = in_sizes[1] / 2;
    const int* esrc = ei;
    const int* edst = ei + E;

    char* p = (char*)d_ws;
    auto alloc = [&](size_t bytes) {
        char* r = p;
        p += (bytes + 255) & ~(size_t)255;
        return (void*)r;
    };
    const int nb  = (N + BSZ - 1) / BSZ;       // p3 buckets (<=256)
    const int NB2 = (E + CHUNK - 1) / CHUNK;   // partition blocks

    int*   cnt = (int*)  alloc((size_t)N * 4);
    float* isd = (float*)alloc((size_t)N * 4);
    int*   ell = (int*)  alloc((size_t)N * CAPD * 4);
    uint*  Tq  = (uint*) alloc((size_t)N * 32 * 4);   // biased-u8 rows, 128 B/node
    float* Ts  = (float*)alloc((size_t)(N + 4) * 4);  // per-row scales
    float* Tsc = (float*)alloc((size_t)(N + 4) * 4);  // Ts*isd (layer-1 agg)
    uint*  Hb  = (uint*) alloc((size_t)N * 64 * 4);   // hidden, fp16 pairs
    uint*  Wt1 = (uint*) alloc(8192 * 4);
    uint*  Wt2 = (uint*) alloc(8192 * 4);
    unsigned* gSorted      = (unsigned*)alloc((size_t)nb * BCAP * 4);
    int*      bucketCursor = (int*)     alloc((size_t)nb * 4);

    const int gblocks = (N + 127) / 128;
    const int ablocks = (N + 15) / 16;   // one node per quarter-wave

    // prep: zero cursors + W transposes
    prep_kernel<<<3, 256, 0, stream>>>(bucketCursor, nb, W1, W2, Wt1, Wt2);
    // partition || layer-1 GEMM (heterogeneous grid, overlapped)
    p3gemm1<<<NB2 + gblocks, 256, 0, stream>>>(esrc, edst, E, nb, NB2, bucketCursor,
                                               gSorted, x, Wt1, Tq, Ts, N);
    // ELL build + cnt/isd + Tsc = Ts*isd
    p4_build<<<4 * nb, 256, 0, stream>>>(gSorted, bucketCursor, nb, N, cnt, isd, ell, Ts, Tsc);
    // Layer-1 agg
    agg_kernel<<<ablocks, 256, 0, stream>>>(Tq, Tsc, ell, cnt, isd, b1, Hb, N);
    // Layer-2 GEMM (isd scale in epilogue)
    gemm2_kernel<<<gblocks, 256, 0, stream>>>(Hb, Wt2, isd, Tq, Ts, N);
    // Layer-2 agg + head
    agg_out_kernel<<<ablocks, 256, 0, stream>>>(Tq, Ts, ell, cnt, isd, b2, Wout, bout, out, N);
}